// Round 14
// baseline (490.734 us; speedup 1.0000x reference)
//
#include <hip/hip_runtime.h>
#include <hip/hip_bf16.h>

#define EPS 1e-6f
#define SCAL 5.0f

typedef __attribute__((ext_vector_type(8))) short bf8v;   // 8 bf16 (4 VGPRs)
typedef __attribute__((ext_vector_type(4))) float f32x4;  // MFMA acc

// ---- workspace (float units) ----
#define OFF_MU     0
#define OFF_LINV   1024
#define OFF_MUA    3072
#define OFF_LINVA  4096
#define OFF_HSUM   6144
#define OFF_ALPHA  6656
#define OFF_REC    23040
#define OFF_R1     32768
#define OFF_R2     (OFF_R1 + 8388608)
#define OFF_R3     (OFF_R2 + 8388608)
#define WS_TOTAL   (OFF_R3 + 16777216)

// NHWC bf16 tensors (offsets in bf16 elements) and fp32 tensors (float offsets)
#define BA_XA   ((size_t)2 * OFF_R3)            // conv1 out [64,4096,64]
#define BA_X2   ((size_t)2 * OFF_R1)            // conv2 out [64,4096,64]
#define OFF_PARTSF OFF_R2                        // parts logits fp32 [b][k][4096] (k-major!)
#define OFF_PROBS  (OFF_R2 + 4194304)            // app probs fp32 [32,16,4096]
#define BA_EA1  ((size_t)2 * OFF_R3)            // ea1 out [32,4096,64]
#define OFF_FXS (OFF_R3 + 4194304)              // f_xs fp32 [32,4096,32]
#define BA_E    ((size_t)2 * OFF_R2)            // encoding [32,4096,64] (48 real + 16 pad)
#define BA_D1   ((size_t)2 * OFF_R1)            // dw1 out [32,4096,64]
#define BA_D2   ((size_t)2 * OFF_R3)            // upconv out [32,16384,32]

// g_wt fp32 layout
#define WT_ESW1 0
#define WT_ESB1 1728
#define WT_ESB2 1792
#define WT_ESBP 1856
#define WT_EAB1 1872
#define WT_EAB2 1936
#define WT_DB1  1968
#define WT_DB2  2032
#define WT_W3P  2064
#define WT_DB3  2928
// g_wp bf16 packed weights [t*2+c][oc][32ic] — fragment = contiguous 1KB, full lines
#define P_WP2  0
#define P_WPP  36864
#define P_WPA1 46080
#define P_WPA2 82944
#define P_WPD1 101376
#define P_WPD2 138240

__device__ __attribute__((aligned(16))) float g_ws[WS_TOTAL];
__device__ __attribute__((aligned(16))) float g_wt[3072];
__device__ __attribute__((aligned(16))) __hip_bfloat16 g_wp[156672];
__device__ int g_isbf16;

__device__ __forceinline__ float selz(bool c, float v) { return c ? v : 0.f; }
__device__ __forceinline__ float cvtbf(short s) {
    return __uint_as_float(((unsigned int)(unsigned short)s) << 16);
}
__device__ __forceinline__ short f2bf(float f) {          // RNE f32->bf16 bits
    unsigned u = __float_as_uint(f);
    u += 0x7fff + ((u >> 16) & 1);
    return (short)(u >> 16);
}
// runtime-dtype external load (adaptive — fixed-dtype builds NaN'd in rounds 1/2/7)
__device__ __forceinline__ float ldin(const void* p, size_t i, int bf) {
    return bf ? __bfloat162float(((const __hip_bfloat16*)p)[i])
              : ((const float*)p)[i];
}

// ---------------- block reductions (blockDim.x == 256) ----------------
__device__ __forceinline__ float block_sum(float v) {
    __shared__ float sb[8];
    for (int off = 32; off; off >>= 1) v += __shfl_down(v, off, 64);
    int lane = threadIdx.x & 63, wid = threadIdx.x >> 6;
    __syncthreads();
    if (lane == 0) sb[wid] = v;
    __syncthreads();
    float r = 0.f;
    for (int i = 0; i < 4; ++i) r += sb[i];
    return r;
}
__device__ __forceinline__ float block_max(float v) {
    __shared__ float sb[8];
    for (int off = 32; off; off >>= 1) v = fmaxf(v, __shfl_down(v, off, 64));
    int lane = threadIdx.x & 63, wid = threadIdx.x >> 6;
    __syncthreads();
    if (lane == 0) sb[wid] = v;
    __syncthreads();
    float r = -1e30f;
    for (int i = 0; i < 4; ++i) r = fmaxf(r, sb[i]);
    return r;
}

// ---------------- dtype probe + init ----------------
__global__ void detect_k(const void* x) {
    const __hip_bfloat16* p = (const __hip_bfloat16*)x;
    int lane = threadIdx.x & 63;
    float v = 0.f;
    for (int i = lane; i < 256; i += 64) {
        float a = fabsf(__bfloat162float(p[i]));
        if (!(a <= 2.0f)) v = 1.f;
    }
    for (int off = 32; off; off >>= 1) v += __shfl_down(v, off, 64);
    if (lane == 0) {
        g_isbf16 = (v == 0.f) ? 1 : 0;
        g_ws[OFF_REC] = 0.f;
    }
}

// ---------------- weight pack: ext dtype -> g_wt fp32 + g_wp bf16 [t*2+c][n][32] ----
__global__ void wpack_k(const void* esw1, const void* esb1, const void* esw2, const void* esb2,
                        const void* eswp, const void* esbp, const void* eaw1, const void* eab1,
                        const void* eaw2, const void* eab2, const void* dw1, const void* db1,
                        const void* dw2, const void* db2, const void* dw3, const void* db3) {
    int bf = g_isbf16;
    int gid0 = blockIdx.x * 256 + threadIdx.x, stride = gridDim.x * 256;
    for (int g = gid0; g < 512; g += stride) g_ws[OFF_HSUM + g] = 0.f;   // heat2 atomics
    for (int g = gid0; g < 1728; g += stride) g_wt[WT_ESW1 + g] = ldin(esw1, g, bf);
    for (int g = gid0; g < 64; g += stride) g_wt[WT_ESB1 + g] = ldin(esb1, g, bf);
    for (int g = gid0; g < 64; g += stride) g_wt[WT_ESB2 + g] = ldin(esb2, g, bf);
    for (int g = gid0; g < 16; g += stride) g_wt[WT_ESBP + g] = ldin(esbp, g, bf);
    for (int g = gid0; g < 64; g += stride) g_wt[WT_EAB1 + g] = ldin(eab1, g, bf);
    for (int g = gid0; g < 32; g += stride) g_wt[WT_EAB2 + g] = ldin(eab2, g, bf);
    for (int g = gid0; g < 64; g += stride) g_wt[WT_DB1 + g] = ldin(db1, g, bf);
    for (int g = gid0; g < 32; g += stride) g_wt[WT_DB2 + g] = ldin(db2, g, bf);
    for (int g = gid0; g < 3; g += stride) g_wt[WT_DB3 + g] = ldin(db3, g, bf);
    for (int g = gid0; g < 864; g += stride) {              // w3p[t][o][k]
        int t = g / 96, o = (g / 32) % 3, k = g & 31;
        g_wt[WT_W3P + g] = ldin(dw3, (size_t)(o * 32 + k) * 9 + t, bf);
    }
    // MFMA weights, fragment-contiguous layout: idx = ((t*2+c)*TOTN + n)*32 + kk,
    // src k = c*32 + kk.
    for (int g = gid0; g < 36864; g += stride) {            // wp2 (TOTN=64)
        int kk = g & 31, n = (g >> 5) & 63, tc = g >> 11;
        int t = tc >> 1, k = (tc & 1) * 32 + kk;
        g_wp[P_WP2 + g] = __float2bfloat16(ldin(esw2, (size_t)(n * 64 + k) * 9 + t, bf));
    }
    for (int g = gid0; g < 9216; g += stride) {             // wpp (TOTN=16)
        int kk = g & 31, n = (g >> 5) & 15, tc = g >> 9;
        int t = tc >> 1, k = (tc & 1) * 32 + kk;
        g_wp[P_WPP + g] = __float2bfloat16(ldin(eswp, (size_t)(n * 64 + k) * 9 + t, bf));
    }
    for (int g = gid0; g < 36864; g += stride) {            // wpa1 (TOTN=64)
        int kk = g & 31, n = (g >> 5) & 63, tc = g >> 11;
        int t = tc >> 1, k = (tc & 1) * 32 + kk;
        g_wp[P_WPA1 + g] = __float2bfloat16(ldin(eaw1, (size_t)(n * 64 + k) * 9 + t, bf));
    }
    for (int g = gid0; g < 18432; g += stride) {            // wpa2 (TOTN=32)
        int kk = g & 31, n = (g >> 5) & 31, tc = g >> 10;
        int t = tc >> 1, k = (tc & 1) * 32 + kk;
        g_wp[P_WPA2 + g] = __float2bfloat16(ldin(eaw2, (size_t)(n * 64 + k) * 9 + t, bf));
    }
    for (int g = gid0; g < 36864; g += stride) {            // wpd1 (TOTN=64, K=48 pad)
        int kk = g & 31, n = (g >> 5) & 63, tc = g >> 11;
        int t = tc >> 1, k = (tc & 1) * 32 + kk;
        float v = (k < 48) ? ldin(dw1, (size_t)(n * 48 + k) * 9 + t, bf) : 0.f;
        g_wp[P_WPD1 + g] = __float2bfloat16(v);
    }
    for (int g = gid0; g < 18432; g += stride) {            // wpd2 (TOTN=32)
        int kk = g & 31, n = (g >> 5) & 31, tc = g >> 10;
        int t = tc >> 1, k = (tc & 1) * 32 + kk;
        g_wp[P_WPD2 + g] = __float2bfloat16(ldin(dw2, (size_t)(n * 64 + k) * 9 + t, bf));
    }
}

// ---------------- conv1 both streams: stride-2 -> NHWC bf16 [64,4096,64], relu ----
__global__ void __launch_bounds__(256)
conv_s2n_k(const void* __restrict__ inA, const void* __restrict__ inB) {
    int bf = g_isbf16;
    int tile = blockIdx.x & 15;
    int b = blockIdx.x >> 4;
    const void* in = (b < 32) ? inA : inB;
    int bb = b & 31;
    int pix = tile * 256 + threadIdx.x;
    int y = pix >> 6, x = pix & 63;
    size_t inb = (size_t)bb * 3 * 16384;
    float acc[64];
    #pragma unroll
    for (int o = 0; o < 64; ++o) acc[o] = g_wt[WT_ESB1 + o];
    int iy0 = 2 * y, ix0 = 2 * x;
    bool my2 = (iy0 + 2 < 128), mx2 = (ix0 + 2 < 128);
    int iy2 = my2 ? iy0 + 2 : 127, ix2 = mx2 ? ix0 + 2 : 127;
    for (int ic = 0; ic < 3; ++ic) {
        size_t pb = inb + ic * 16384;
        float t[9];
        t[0] = ldin(in, pb + iy0 * 128 + ix0, bf);
        t[1] = ldin(in, pb + iy0 * 128 + ix0 + 1, bf);
        t[2] = selz(mx2, ldin(in, pb + iy0 * 128 + ix2, bf));
        t[3] = ldin(in, pb + (iy0 + 1) * 128 + ix0, bf);
        t[4] = ldin(in, pb + (iy0 + 1) * 128 + ix0 + 1, bf);
        t[5] = selz(mx2, ldin(in, pb + (iy0 + 1) * 128 + ix2, bf));
        t[6] = selz(my2, ldin(in, pb + iy2 * 128 + ix0, bf));
        t[7] = selz(my2, ldin(in, pb + iy2 * 128 + ix0 + 1, bf));
        t[8] = selz(my2 && mx2, ldin(in, pb + iy2 * 128 + ix2, bf));
        #pragma unroll
        for (int o = 0; o < 64; ++o) {
            const float* wr = g_wt + WT_ESW1 + (o * 3 + ic) * 9;
            float a = acc[o];
            #pragma unroll
            for (int j = 0; j < 9; ++j) a = fmaf(t[j], wr[j], a);
            acc[o] = a;
        }
    }
    __hip_bfloat16* out = (__hip_bfloat16*)g_ws + BA_XA + ((size_t)b * 4096 + pix) * 64;
    #pragma unroll
    for (int o = 0; o < 64; ++o) out[o] = __float2bfloat16(fmaxf(acc[o], 0.f));
}

// ---------------- full-channel LDS staging: TR rows x 66 px x 64 ch, swizzled ----
// 16B chunks, slot = j ^ (P & 7): px-stride 128 B — 0 conflicts for the ld_a
// access shape ONLY (j uniform per quarter-wave, P consecutive). r12 lesson.
template<int TR>
__device__ __forceinline__ void stage_tile(__hip_bfloat16* sA,
                                           const __hip_bfloat16* __restrict__ inb, int y0) {
    for (int g = threadIdx.x; g < TR * 512; g += 256) {
        int r = g >> 9;                 // 0..TR-1
        int rem = g & 511;
        int px = rem >> 3, j = rem & 7;
        int yy = y0 - 1 + r;
        int P = px + 1;
        bf8v v = (bf8v){0, 0, 0, 0, 0, 0, 0, 0};
        if (yy >= 0 && yy <= 63)
            v = *(const bf8v*)(inb + ((size_t)(yy * 64 + px) * 64 + j * 8));
        *(bf8v*)(sA + ((r * 66 + P) * 64 + ((j ^ (P & 7)) * 8))) = v;
    }
    if (threadIdx.x < TR * 16) {        // zero pads P=0 and P=65
        int g = threadIdx.x;
        int r = g >> 4, rem = g & 15, side = rem >> 3, j = rem & 7;
        int P = side ? 65 : 0;
        *(bf8v*)(sA + ((r * 66 + P) * 64 + ((j ^ (P & 7)) * 8))) = (bf8v){0, 0, 0, 0, 0, 0, 0, 0};
    }
}

// ---------------- pipelined fragment loaders (it is compile-time in unrolled loops) ---
template<int MS>
__device__ __forceinline__ void ld_a(const __hip_bfloat16* sA, int it, int rowIn,
                                     int l15, int quad, bf8v (&a)[MS]) {
    const int t = it >> 1, c = it & 1;
    const int dy = t / 3 - 1, dx = t % 3 - 1;
    const int r = rowIn + 1 + dy;
    const int j = c * 4 + quad;
    #pragma unroll
    for (int ms = 0; ms < MS; ++ms) {
        int P = ms * 16 + l15 + dx + 1;
        a[ms] = *(const bf8v*)(sA + ((r * 66 + P) * 64 + ((j ^ (P & 7)) * 8)));
    }
}
// two-row variant: loads 4-px-block fragments for rows rowbase, rowbase+1
template<int MS>
__device__ __forceinline__ void ld_a2(const __hip_bfloat16* sA, int it, int rowbase,
                                      int l15, int quad, bf8v (&a)[2][MS]) {
    const int t = it >> 1, c = it & 1;
    const int dy = t / 3 - 1, dx = t % 3 - 1;
    const int j = c * 4 + quad;
    #pragma unroll
    for (int rp = 0; rp < 2; ++rp) {
        const int r = rowbase + rp + 1 + dy;
        #pragma unroll
        for (int ms = 0; ms < MS; ++ms) {
            int P = ms * 16 + l15 + dx + 1;
            a[rp][ms] = *(const bf8v*)(sA + ((r * 66 + P) * 64 + ((j ^ (P & 7)) * 8)));
        }
    }
}
// weight fragment: it = t*2+c indexes the fragment-contiguous pack directly.
template<int TOTN, int NS>
__device__ __forceinline__ void ld_b(int it, int ocoff, int l15, int quad, int wp_off,
                                     bf8v (&bv)[NS]) {
    #pragma unroll
    for (int ns = 0; ns < NS; ++ns)
        bv[ns] = *(const bf8v*)(g_wp + wp_off +
                 ((size_t)(it * TOTN + ocoff + ns * 16 + l15) * 32 + quad * 8));
}

// ---------------- single-row MFMA body (parts pass only: NS=1, wave=row) ----------
template<int TOTN, int NS, int MS>
__device__ __forceinline__ void conv_body(const __hip_bfloat16* sA, int rowIn,
                                          int l15, int quad, int wp_off,
                                          f32x4 (&acc)[MS][NS]) {
    bf8v bq[3][NS];
    bf8v a[2][MS];
    ld_b<TOTN, NS>(0, 0, l15, quad, wp_off, bq[0]);
    ld_b<TOTN, NS>(1, 0, l15, quad, wp_off, bq[1]);
    ld_a<MS>(sA, 0, rowIn, l15, quad, a[0]);
    #pragma unroll
    for (int it = 0; it < 18; ++it) {
        if (it + 2 < 18) ld_b<TOTN, NS>(it + 2, 0, l15, quad, wp_off, bq[(it + 2) % 3]);
        if (it + 1 < 18) ld_a<MS>(sA, it + 1, rowIn, l15, quad, a[(it + 1) & 1]);
        #pragma unroll
        for (int ns = 0; ns < NS; ++ns)
            #pragma unroll
            for (int ms = 0; ms < MS; ++ms)
                acc[ms][ns] = __builtin_amdgcn_mfma_f32_16x16x32_bf16(
                    a[it & 1][ms], bq[it % 3][ns], acc[ms][ns], 0, 0, 0);
    }
}

// ---------------- 2-row x NSW-group MFMA body (weight-traffic-minimized) ----------
template<int TOTN, int NSW, int MS>
__device__ __forceinline__ void conv_body2(const __hip_bfloat16* sA, int rowbase, int ocoff,
                                           int l15, int quad, int wp_off,
                                           f32x4 (&acc)[2][MS][NSW]) {
    bf8v bq[3][NSW];
    bf8v a[2][2][MS];
    ld_b<TOTN, NSW>(0, ocoff, l15, quad, wp_off, bq[0]);
    ld_b<TOTN, NSW>(1, ocoff, l15, quad, wp_off, bq[1]);
    ld_a2<MS>(sA, 0, rowbase, l15, quad, a[0]);
    #pragma unroll
    for (int it = 0; it < 18; ++it) {
        if (it + 2 < 18) ld_b<TOTN, NSW>(it + 2, ocoff, l15, quad, wp_off, bq[(it + 2) % 3]);
        if (it + 1 < 18) ld_a2<MS>(sA, it + 1, rowbase, l15, quad, a[(it + 1) & 1]);
        #pragma unroll
        for (int rp = 0; rp < 2; ++rp)
            #pragma unroll
            for (int ns = 0; ns < NSW; ++ns)
                #pragma unroll
                for (int ms = 0; ms < MS; ++ms)
                    acc[rp][ms][ns] = __builtin_amdgcn_mfma_f32_16x16x32_bf16(
                        a[it & 1][rp][ms], bq[it % 3][ns], acc[rp][ms][ns], 0, 0, 0);
    }
}

// ---------------- epilogue (2-row) ----------------
template<int TOTN, int NSW, int OUTF32, int RELU>
__device__ __forceinline__ void epi_2r(f32x4 (&acc)[2][4][NSW], int bO, int y0, int rowbase,
                                       int ocoff, int l15, int quad, int bias_off,
                                       size_t out_off) {
    #pragma unroll
    for (int rp = 0; rp < 2; ++rp) {
        int y = y0 + rowbase + rp;
        #pragma unroll
        for (int ns = 0; ns < NSW; ++ns) {
            float bias = g_wt[bias_off + ocoff + ns * 16 + l15];
            #pragma unroll
            for (int ms = 0; ms < 4; ++ms) {
                #pragma unroll
                for (int r = 0; r < 4; ++r) {
                    int pix = ms * 16 + quad * 4 + r;
                    float v = acc[rp][ms][ns][r] + bias;
                    if (RELU) v = fmaxf(v, 0.f);
                    size_t o = out_off + ((size_t)(bO * 4096 + y * 64 + pix)) * TOTN +
                               ocoff + ns * 16 + l15;
                    if (OUTF32) g_ws[o] = v;
                    else ((__hip_bfloat16*)g_ws)[o] = __float2bfloat16(v);
                }
            }
        }
    }
}

// ---------------- 2-row-block 16-oc-wave MFMA conv (TOTN=64) ----------------------
// r14: third application of the r7 weight-traffic lever. Block = 2 output rows
// (stage_tile<4>, 33792 B -> 4 blocks/CU); waves = 4 oc-groups of 16; per-wave
// weight bytes 36->18 KB. b in LOW bits of blockIdx pins each batch's 32 row-tiles
// to one XCD (pea-proven L2 reuse). acc 32 + A-dbuf 64 + bq 12 ~ 130 VGPR < 170.
template<int LOGB, int OUTF32, int RELU>
__global__ void __launch_bounds__(256) __attribute__((amdgpu_waves_per_eu(2, 3)))
conv_mfl1_k(size_t in_off, int wp_off, int bias_off, size_t out_off) {
    __shared__ __hip_bfloat16 sA[4 * 66 * 64];
    int wid = threadIdx.x >> 6, lane = threadIdx.x & 63;
    int l15 = lane & 15, quad = lane >> 4;
    int b = blockIdx.x & ((1 << LOGB) - 1);
    int y0 = (int)(blockIdx.x >> LOGB) * 2;
    int ocoff = wid * 16;
    const __hip_bfloat16* inb = (const __hip_bfloat16*)g_ws + in_off + (size_t)b * 4096 * 64;
    stage_tile<4>(sA, inb, y0);
    __syncthreads();
    f32x4 acc[2][4][1];
    #pragma unroll
    for (int rp = 0; rp < 2; ++rp)
        #pragma unroll
        for (int ms = 0; ms < 4; ++ms) acc[rp][ms][0] = (f32x4){0.f, 0.f, 0.f, 0.f};
    conv_body2<64, 1, 4>(sA, 0, ocoff, l15, quad, wp_off, acc);
    epi_2r<64, 1, OUTF32, RELU>(acc, b, y0, 0, ocoff, l15, quad, bias_off, out_off);
}

// ---------------- 4-row-block MFMA conv (fxs TOTN=32: waves = 2 rowpairs x 2 og) --
template<int TOTN, int NSW, int OUTF32, int RELU>
__global__ void __launch_bounds__(256) __attribute__((amdgpu_waves_per_eu(2, 3)))
conv_mfl_k(size_t in_off, int wp_off, int bias_off, size_t out_off) {
    __shared__ __hip_bfloat16 sA[6 * 66 * 64];
    int wid = threadIdx.x >> 6, lane = threadIdx.x & 63;
    int l15 = lane & 15, quad = lane >> 4;
    int b = blockIdx.x >> 4, y0 = (blockIdx.x & 15) * 4;
    int og = wid & 1, rowbase = (wid >> 1) * 2;
    int ocoff = og * NSW * 16;
    const __hip_bfloat16* inb = (const __hip_bfloat16*)g_ws + in_off + (size_t)b * 4096 * 64;
    stage_tile<6>(sA, inb, y0);
    __syncthreads();
    f32x4 acc[2][4][NSW];
    #pragma unroll
    for (int rp = 0; rp < 2; ++rp)
        #pragma unroll
        for (int ms = 0; ms < 4; ++ms)
            #pragma unroll
            for (int ns = 0; ns < NSW; ++ns) acc[rp][ms][ns] = (f32x4){0.f, 0.f, 0.f, 0.f};
    conv_body2<TOTN, NSW, 4>(sA, rowbase, ocoff, l15, quad, wp_off, acc);
    epi_2r<TOTN, NSW, OUTF32, RELU>(acc, b, y0, rowbase, ocoff, l15, quad, bias_off, out_off);
}

// ---------------- fused parts(all 64 b) + ea1(app half) from ONE X2 staging ------
__global__ void __launch_bounds__(256) __attribute__((amdgpu_waves_per_eu(2, 3)))
conv_pea_k() {
    __shared__ __hip_bfloat16 sA[6 * 66 * 64];
    int wid = threadIdx.x >> 6, lane = threadIdx.x & 63;
    int l15 = lane & 15, quad = lane >> 4;
    int b = blockIdx.x & 63;
    int y0 = (int)(blockIdx.x >> 6) * 4;
    const __hip_bfloat16* inb = (const __hip_bfloat16*)g_ws + BA_X2 + (size_t)b * 4096 * 64;
    stage_tile<6>(sA, inb, y0);
    __syncthreads();
    // pass 1: parts logits (16 oc): wave = row, result kept in regs
    f32x4 accP[4][1];
    #pragma unroll
    for (int ms = 0; ms < 4; ++ms) accP[ms][0] = (f32x4){0.f, 0.f, 0.f, 0.f};
    conv_body<16, 1, 4>(sA, wid, l15, quad, P_WPP, accP);
    // pass 2: e_alpha conv1 (64 oc): wave = 2 rows x 32 oc (app half only)
    if (b >= 32) {
        int og = wid & 1, rowbase = (wid >> 1) * 2;
        int ocoff = og * 32;
        f32x4 accE[2][4][2];
        #pragma unroll
        for (int rp = 0; rp < 2; ++rp)
            #pragma unroll
            for (int ms = 0; ms < 4; ++ms)
                #pragma unroll
                for (int ns = 0; ns < 2; ++ns) accE[rp][ms][ns] = (f32x4){0.f, 0.f, 0.f, 0.f};
        conv_body2<64, 2, 4>(sA, rowbase, ocoff, l15, quad, P_WPA1, accE);
        epi_2r<64, 2, 0, 1>(accE, b - 32, y0, rowbase, ocoff, l15, quad, WT_EAB1, BA_EA1);
    }
    // transpose parts through LDS (sA no longer needed), store [b][k][4096] coalesced
    __syncthreads();
    float* tb = (float*)sA;                          // 16 k x 260-stride (16B-aligned rows)
    float biasP = g_wt[WT_ESBP + l15];
    #pragma unroll
    for (int ms = 0; ms < 4; ++ms)
        #pragma unroll
        for (int r = 0; r < 4; ++r)
            tb[l15 * 260 + wid * 64 + ms * 16 + quad * 4 + r] = accP[ms][0][r] + biasP;
    __syncthreads();
    int k = threadIdx.x >> 4, xo = (threadIdx.x & 15) * 16;
    float* dst = g_ws + OFF_PARTSF + ((size_t)(b * 16 + k)) * 4096 + y0 * 64 + xo;
    const float* src = tb + k * 260 + xo;
    #pragma unroll
    for (int i = 0; i < 16; i += 4)
        *(f32x4*)(dst + i) = *(const f32x4*)(src + i);
}

// ---------------- LDS-staged MFMA decoder conv2 + 2x nearest upsample ----------------
__global__ void __launch_bounds__(256) __attribute__((amdgpu_waves_per_eu(2, 3)))
conv_upmf2_k(size_t in_off, int wp_off, int bias_off, size_t out_off) {
    __shared__ __hip_bfloat16 sA[4 * 66 * 64];   // 33792 B -> 4 blocks/CU
    int wid = threadIdx.x >> 6, lane = threadIdx.x & 63;
    int l15 = lane & 15, quad = lane >> 4;
    int b = blockIdx.x >> 5, y0 = (blockIdx.x & 31) * 4;
    int ri0 = (y0 >> 1) - 1;
    const __hip_bfloat16* inb = (const __hip_bfloat16*)g_ws + in_off + (size_t)b * 4096 * 64;
    for (int g = threadIdx.x; g < 2048; g += 256) {
        int r = g >> 9;                 // 0..3
        int rem = g & 511;
        int px = rem >> 3, j = rem & 7;
        int yi = ri0 + r;
        int P = px + 1;
        bf8v v = (bf8v){0, 0, 0, 0, 0, 0, 0, 0};
        if (yi >= 0 && yi <= 63)
            v = *(const bf8v*)(inb + ((size_t)(yi * 64 + px) * 64 + j * 8));
        *(bf8v*)(sA + ((r * 66 + P) * 64 + ((j ^ (P & 7)) * 8))) = v;
    }
    if (threadIdx.x < 64) {             // zero pads P=0 and P=65
        int g = threadIdx.x;
        int r = g >> 4, rem = g & 15, side = rem >> 3, j = rem & 7;
        int P = side ? 65 : 0;
        *(bf8v*)(sA + ((r * 66 + P) * 64 + ((j ^ (P & 7)) * 8))) = (bf8v){0, 0, 0, 0, 0, 0, 0, 0};
    }
    __syncthreads();
    int og = wid & 1, rowbase = (wid >> 1) * 2;
    f32x4 acc[2][8];
    #pragma unroll
    for (int rp = 0; rp < 2; ++rp)
        #pragma unroll
        for (int ms = 0; ms < 8; ++ms) acc[rp][ms] = (f32x4){0.f, 0.f, 0.f, 0.f};
    bf8v bq[3][1];
    ld_b<32, 1>(0, og * 16, l15, quad, wp_off, bq[0]);
    ld_b<32, 1>(1, og * 16, l15, quad, wp_off, bq[1]);
    #pragma unroll
    for (int it = 0; it < 18; ++it) {
        if (it + 2 < 18) ld_b<32, 1>(it + 2, og * 16, l15, quad, wp_off, bq[(it + 2) % 3]);
        const int t = it >> 1, c = it & 1;
        const int dy = t / 3 - 1, dx = t % 3 - 1;
        #pragma unroll
        for (int rp = 0; rp < 2; ++rp) {
            int yy = y0 + rowbase + rp + dy;
            if (yy >= 0 && yy <= 127) {       // wave-uniform per rp
                int r = (yy >> 1) - ri0;      // 0..3
                int j = c * 4 + quad;
                bf8v a[8];
                #pragma unroll
                for (int ms = 0; ms < 8; ++ms) {
                    int xx = ms * 16 + l15 + dx;
                    int P = (xx < 0) ? 0 : ((xx > 127) ? 65 : ((xx >> 1) + 1));
                    a[ms] = *(const bf8v*)(sA + ((r * 66 + P) * 64 + ((j ^ (P & 7)) * 8)));
                }
                #pragma unroll
                for (int ms = 0; ms < 8; ++ms)
                    acc[rp][ms] = __builtin_amdgcn_mfma_f32_16x16x32_bf16(a[ms], bq[it % 3][0], acc[rp][ms], 0, 0, 0);
            }
        }
    }
    float bias = g_wt[bias_off + og * 16 + l15];
    #pragma unroll
    for (int rp = 0; rp < 2; ++rp) {
        int y = y0 + rowbase + rp;
        #pragma unroll
        for (int ms = 0; ms < 8; ++ms) {
            #pragma unroll
            for (int r = 0; r < 4; ++r) {
                int pix = ms * 16 + quad * 4 + r;
                float v = fmaxf(acc[rp][ms][r] + bias, 0.f);
                size_t o = out_off + ((size_t)(b * 16384 + y * 128 + pix)) * 32 + og * 16 + l15;
                ((__hip_bfloat16*)g_ws)[o] = __float2bfloat16(v);
            }
        }
    }
}

// ---------------- fused softmax+moments: parts logits fp32 [b][k][4096] ----------------
__global__ void sm_mom3_k() {
    int bk = blockIdx.x;
    int b = bk >> 4;
    int app = (b >= 32);
    const float* P = g_ws + OFF_PARTSF + (size_t)bk * 4096;
    float r[16];
    #pragma unroll
    for (int j = 0; j < 16; ++j) r[j] = P[threadIdx.x + j * 256];
    float m = r[0];
    #pragma unroll
    for (int j = 1; j < 16; ++j) m = fmaxf(m, r[j]);
    m = block_max(m);
    float s = 0.f;
    #pragma unroll
    for (int j = 0; j < 16; ++j) { r[j] = __expf(r[j] - m); s += r[j]; }
    s = block_sum(s);
    float inv = 1.0f / s;
    float sy = 0, sx = 0, syy = 0, sxy = 0, sxx = 0;
    #pragma unroll
    for (int j = 0; j < 16; ++j) {
        float pv = r[j] * inv;
        int i = threadIdx.x + j * 256;
        if (app) g_ws[OFF_PROBS + (size_t)(bk - 512) * 4096 + i] = pv;
        float gy = -1.0f + (i >> 6) * (2.0f / 63.0f);
        float gx = -1.0f + (i & 63) * (2.0f / 63.0f);
        sy += pv * gy; sx += pv * gx;
        syy += pv * gy * gy; sxy += pv * gy * gx; sxx += pv * gx * gx;
    }
    sy = block_sum(sy); sx = block_sum(sx);
    syy = block_sum(syy); sxy = block_sum(sxy); sxx = block_sum(sxx);
    if (threadIdx.x == 0) {
        float c00 = syy - sy * sy, c01 = sxy - sy * sx, c11 = sxx - sx * sx;
        float a = sqrtf(fmaxf(c00 + EPS, 1e-12f));
        float bb = c01 / (a + EPS);
        float cc = sqrtf(fmaxf(c11 - bb * bb, 0.f) + EPS);
        float det = a * cc;
        float sc = SCAL / (det + EPS);
        int idx = app ? (bk - 512) : bk;
        int mu_off = app ? OFF_MUA : OFF_MU;
        int linv_off = app ? OFF_LINVA : OFF_LINV;
        g_ws[mu_off + idx * 2 + 0] = sy;
        g_ws[mu_off + idx * 2 + 1] = sx;
        g_ws[linv_off + idx * 4 + 0] = cc * sc;
        g_ws[linv_off + idx * 4 + 1] = 0.f;
        g_ws[linv_off + idx * 4 + 2] = -bb * sc;
        g_ws[linv_off + idx * 4 + 3] = a * sc;
    }
}

// ---------------- alpha[b,k,f] = sum_hw probs[b,k,hw] * fxs[b,hw,f] (both fp32) ----------------
__global__ void alpha2_k() {
    int b = blockIdx.x & 31, k = blockIdx.x >> 5;
    int bk = b * 16 + k;
    __shared__ float pl[4096];
    const float* pr = g_ws + OFF_PROBS + (size_t)bk * 4096;
    for (int i = threadIdx.x; i < 4096; i += 256) pl[i] = pr[i];
    __syncthreads();
    float acc[32];
    #pragma unroll
    for (int f = 0; f < 32; ++f) acc[f] = 0.f;
    for (int i = threadIdx.x; i < 4096; i += 256) {
        float pv = pl[i];
        const float* fp = g_ws + OFF_FXS + (size_t)(b * 4096 + i) * 32;
        #pragma unroll
        for (int f = 0; f < 32; ++f) acc[f] = fmaf(pv, fp[f], acc[f]);
    }
    __shared__ float sw[4][32];
    int lane = threadIdx.x & 63, wid = threadIdx.x >> 6;
    #pragma unroll
    for (int f = 0; f < 32; ++f)
        for (int off = 32; off; off >>= 1) acc[f] += __shfl_down(acc[f], off, 64);
    if (lane == 0) {
        #pragma unroll
        for (int f = 0; f < 32; ++f) sw[wid][f] = acc[f];
    }
    __syncthreads();
    if (threadIdx.x < 32)
        g_ws[OFF_ALPHA + bk * 32 + threadIdx.x] =
            sw[0][threadIdx.x] + sw[1][threadIdx.x] + sw[2][threadIdx.x] + sw[3][threadIdx.x];
}

// ---------------- heat -> E NHWC bf16 ch[0..16) vector writes, + hsum atomics ----------------
__global__ void heat2_k() {
    int tile = blockIdx.x & 15, b = blockIdx.x >> 4;
    __shared__ float hs[16];
    if (threadIdx.x < 16) hs[threadIdx.x] = 0.f;
    __syncthreads();
    int pix = tile * 256 + threadIdx.x;
    float gy = -1.0f + (pix >> 6) * (2.0f / 63.0f);
    float gx = -1.0f + (pix & 63) * (2.0f / 63.0f);
    bf8v e0, e1;
    float hv[16];
    #pragma unroll
    for (int k = 0; k < 16; ++k) {
        int bk = b * 16 + k;
        float m0 = g_ws[OFF_MU + bk * 2], m1 = g_ws[OFF_MU + bk * 2 + 1];
        float L00 = g_ws[OFF_LINV + bk * 4 + 0], L10 = g_ws[OFF_LINV + bk * 4 + 2],
              L11 = g_ws[OFF_LINV + bk * 4 + 3];
        float d0 = gy - m0, d1 = gx - m1;
        float p0 = d0 * L00 + d1 * L10;
        float p1 = d1 * L11;
        float h = 1.0f / (1.0f + p0 * p0 + p1 * p1);
        hv[k] = h;
        short sbits = f2bf(h);
        if (k < 8) e0[k] = sbits; else e1[k - 8] = sbits;
    }
    __hip_bfloat16* E = (__hip_bfloat16*)g_ws + BA_E + (size_t)(b * 4096 + pix) * 64;
    *(bf8v*)E = e0;
    *(bf8v*)(E + 8) = e1;
    #pragma unroll
    for (int k = 0; k < 16; ++k) {
        float v = hv[k];
        for (int off = 32; off; off >>= 1) v += __shfl_down(v, off, 64);
        if ((threadIdx.x & 63) == 0) atomicAdd(&hs[k], v);
    }
    __syncthreads();
    if (threadIdx.x < 16)
        atomicAdd(&g_ws[OFF_HSUM + b * 16 + threadIdx.x], hs[threadIdx.x]);
}

// ---------------- fmap -> E ch[16..48), zero ch[48..64) ----------------
__global__ void fmap2_k() {
    int tile = blockIdx.x & 15, b = blockIdx.x >> 4;
    __shared__ float coef[16][32];
    for (int i = threadIdx.x; i < 512; i += 256) {
        int k = i >> 5, f = i & 31;
        coef[k][f] = g_ws[OFF_ALPHA + (b * 16 + k) * 32 + f] /
                     (g_ws[OFF_HSUM + b * 16 + k] + EPS);
    }
    __syncthreads();
    int pix = tile * 256 + threadIdx.x;
    __hip_bfloat16* E = (__hip_bfloat16*)g_ws + BA_E + (size_t)(b * 4096 + pix) * 64;
    float h[16];
    #pragma unroll
    for (int k = 0; k < 16; ++k) h[k] = __bfloat162float(E[k]);
    #pragma unroll
    for (int f = 0; f < 32; ++f) {
        float a = 0.f;
        #pragma unroll
        for (int k = 0; k < 16; ++k) a = fmaf(h[k], coef[k][f], a);
        E[16 + f] = __float2bfloat16(a);
    }
    #pragma unroll
    for (int z = 48; z < 64; ++z) E[z] = __float2bfloat16(0.f);
}

// ---------------- final conv(32->3) + sigmoid -> out, fused rec-loss ----------------
// r13: tap double-buffer + two independent pixel chains (allocator cannot merge).
__device__ __forceinline__ void ld_tap9(const short* __restrict__ D2, int y, int x, int t,
                                        bf8v (&dst)[4]) {
    int dy = t / 3 - 1, dx = t % 3 - 1;
    int yy = y + dy, xx = x + dx;
    bool ok = ((unsigned)yy < 128u) && ((unsigned)xx < 128u);
    const short* sp = D2 + (size_t)((ok ? yy : y) * 128 + (ok ? xx : x)) * 32;
    const bf8v zv = (bf8v){0, 0, 0, 0, 0, 0, 0, 0};
    #pragma unroll
    for (int c = 0; c < 4; ++c) {
        bf8v tmp = *(const bf8v*)(sp + c * 8);
        dst[c] = ok ? tmp : zv;
    }
}
__device__ __forceinline__ void fma_tap(const bf8v (&v)[4], int t, float (&acc)[3]) {
    #pragma unroll
    for (int c = 0; c < 4; ++c)
        #pragma unroll
        for (int j = 0; j < 8; ++j) {
            float av = cvtbf(v[c][j]);
            int kk = c * 8 + j;
            acc[0] = fmaf(av, g_wt[WT_W3P + (t * 3 + 0) * 32 + kk], acc[0]);
            acc[1] = fmaf(av, g_wt[WT_W3P + (t * 3 + 1) * 32 + kk], acc[1]);
            acc[2] = fmaf(av, g_wt[WT_W3P + (t * 3 + 2) * 32 + kk], acc[2]);
        }
}
__global__ void __launch_bounds__(256)
conv_sign_k(const void* __restrict__ ximg, void* __restrict__ outp) {
    int bf = g_isbf16;
    int tile = blockIdx.x & 31, b = blockIdx.x >> 5;
    int pix0 = tile * 512 + threadIdx.x;
    int pix1 = pix0 + 256;
    int y0p = pix0 >> 7, x0p = pix0 & 127;
    int y1p = pix1 >> 7, x1p = pix1 & 127;
    const short* D2 = (const short*)((const __hip_bfloat16*)g_ws + BA_D2 + (size_t)b * 16384 * 32);
    float acc0[3], acc1[3];
    #pragma unroll
    for (int o = 0; o < 3; ++o) { acc0[o] = g_wt[WT_DB3 + o]; acc1[o] = acc0[o]; }
    bf8v vA0[4], vB0[4], vA1[4], vB1[4];
    ld_tap9(D2, y0p, x0p, 0, vA0);
    ld_tap9(D2, y1p, x1p, 0, vA1);
    #pragma unroll 1
    for (int tt = 0; tt < 4; ++tt) {          // taps 2tt, 2tt+1; preload 2tt+2
        int t0 = 2 * tt, t1 = 2 * tt + 1;
        ld_tap9(D2, y0p, x0p, t1, vB0);
        ld_tap9(D2, y1p, x1p, t1, vB1);
        fma_tap(vA0, t0, acc0);
        fma_tap(vA1, t0, acc1);
        ld_tap9(D2, y0p, x0p, t1 + 1, vA0);   // t1+1 <= 8, always valid tap
        ld_tap9(D2, y1p, x1p, t1 + 1, vA1);
        fma_tap(vB0, t1, acc0);
        fma_tap(vB1, t1, acc1);
    }
    fma_tap(vA0, 8, acc0);
    fma_tap(vA1, 8, acc1);
    float es = 0.f;
    #pragma unroll
    for (int o = 0; o < 3; ++o) {
        float v = 1.0f / (1.0f + __expf(-acc0[o]));
        size_t oidx = ((size_t)b * 3 + o) * 16384 + pix0;
        if (bf) ((__hip_bfloat16*)outp)[oidx] = __float2bfloat16(v);
        else    ((float*)outp)[oidx] = v;
        float e = ldin(ximg, oidx, bf) - v;
        es += e * e;
        float v1 = 1.0f / (1.0f + __expf(-acc1[o]));
        size_t oidx1 = ((size_t)b * 3 + o) * 16384 + pix1;
        if (bf) ((__hip_bfloat16*)outp)[oidx1] = __float2bfloat16(v1);
        else    ((float*)outp)[oidx1] = v1;
        float e1 = ldin(ximg, oidx1, bf) - v1;
        es += e1 * e1;
    }
    float s = block_sum(es);
    if (threadIdx.x == 0) atomicAdd(&g_ws[OFF_REC], s);
}

// ---------------- scalar loss ----------------
__global__ void loss_k(const void* __restrict__ coord,
                       const void* __restrict__ vec,
                       void* __restrict__ outp) {
    int bf = g_isbf16;
    const float* mu = g_ws + OFF_MU;
    const float* linv = g_ws + OFF_LINV;
    const float* mu_a = g_ws + OFF_MUA;
    const float* linv_a = g_ws + OFF_LINVA;
    float s1 = 0, s2 = 0, s3 = 0;
    for (int i = threadIdx.x; i < 1024; i += 256) {
        float d = mu[i] - mu_a[i];
        s1 += d * d;
        float t = ldin(coord, i, bf) + ldin(vec, i, bf);
        float d3 = mu_a[i] - t;
        s3 += d3 * d3;
    }
    for (int i = threadIdx.x; i < 2048; i += 256) {
        float d = linv[i] - linv_a[i];
        s2 += d * d;
    }
    s1 = block_sum(s1);
    s2 = block_sum(s2);
    s3 = block_sum(s3);
    if (threadIdx.x == 0) {
        float loss = g_ws[OFF_REC] / 1572864.0f + s1 / 1024.0f + 0.01f * (s2 / 2048.0f)
                   + s3 / 1024.0f;
        if (bf) ((__hip_bfloat16*)outp)[1572864] = __float2bfloat16(loss);
        else    ((float*)outp)[1572864] = loss;
    }
}

extern "C" void kernel_launch(void* const* d_in, const int* in_sizes, int n_in,
                              void* d_out, int out_size, void* d_ws, size_t ws_size,
                              hipStream_t stream) {
    const void* x     = d_in[0];
    const void* x_st  = d_in[1];
    const void* x_at  = d_in[2];
    const void* coord = d_in[3];
    const void* vec   = d_in[4];

    dim3 blk(256);

    detect_k<<<1, 64, 0, stream>>>(x);
    wpack_k<<<64, blk, 0, stream>>>(
        d_in[5],  d_in[6],  d_in[7],  d_in[8],
        d_in[9],  d_in[10], d_in[11], d_in[12],
        d_in[13], d_in[14], d_in[15], d_in[16],
        d_in[17], d_in[18], d_in[19], d_in[20]);

    // ---- encoder: conv1 (merged 64-oc) -> XA; conv2 (2-row/16-oc waves) -> X2 ----
    conv_s2n_k<<<64 * 16, blk, 0, stream>>>(x_at, x_st);
    conv_mfl1_k<6, 0, 1><<<2048, blk, 0, stream>>>(BA_XA, P_WP2, WT_ESB2, BA_X2);

    // ---- fused: parts logits (all b, k-major via LDS transpose) + ea1 (app half) ----
    conv_pea_k<<<1024, blk, 0, stream>>>();
    sm_mom3_k<<<1024, blk, 0, stream>>>();

    // ---- e_alpha conv2 -> FXS fp32; alpha (XCD-swizzled) ----
    conv_mfl_k<32, 1, 1, 0><<<512, blk, 0, stream>>>(BA_EA1, P_WPA2, WT_EAB2, (size_t)OFF_FXS);
    alpha2_k<<<512, blk, 0, stream>>>();

    // ---- encoding E (NHWC bf16, 48+16pad): heat (vectorized) + fmap ----
    heat2_k<<<512, blk, 0, stream>>>();
    fmap2_k<<<512, blk, 0, stream>>>();

    // ---- decoder: dw1 (2-row/16-oc waves) -> D1; upconv -> D2; sig conv -> out ----
    conv_mfl1_k<5, 0, 1><<<1024, blk, 0, stream>>>(BA_E, P_WPD1, WT_DB1, BA_D1);
    conv_upmf2_k<<<1024, blk, 0, stream>>>(BA_D1, P_WPD2, WT_DB2, BA_D2);
    conv_sign_k<<<32 * 32, blk, 0, stream>>>(x, d_out);

    // ---- loss ----
    loss_k<<<1, blk, 0, stream>>>(coord, vec, d_out);
}

// Round 15
// 374.597 us; speedup vs baseline: 1.3100x; 1.3100x over previous
//
#include <hip/hip_runtime.h>
#include <hip/hip_bf16.h>

#define EPS 1e-6f
#define SCAL 5.0f

typedef __attribute__((ext_vector_type(8))) short bf8v;   // 8 bf16 (4 VGPRs)
typedef __attribute__((ext_vector_type(4))) float f32x4;  // MFMA acc

// ---- workspace (float units) ----
#define OFF_MU     0
#define OFF_LINV   1024
#define OFF_MUA    3072
#define OFF_LINVA  4096
#define OFF_HSUM   6144
#define OFF_ALPHA  6656
#define OFF_REC    23040
#define OFF_R1     32768
#define OFF_R2     (OFF_R1 + 8388608)
#define OFF_R3     (OFF_R2 + 8388608)
#define WS_TOTAL   (OFF_R3 + 16777216)

// NHWC bf16 tensors (offsets in bf16 elements) and fp32 tensors (float offsets)
#define BA_XA   ((size_t)2 * OFF_R3)            // conv1 out [64,4096,64]
#define BA_X2   ((size_t)2 * OFF_R1)            // conv2 out [64,4096,64]
#define OFF_PARTSF OFF_R2                        // parts logits fp32 [b][k][4096] (k-major!)
#define OFF_PROBS  (OFF_R2 + 4194304)            // app probs fp32 [32,16,4096]
#define BA_EA1  ((size_t)2 * OFF_R3)            // ea1 out [32,4096,64]
#define OFF_FXS (OFF_R3 + 4194304)              // f_xs fp32 [32,4096,32]
#define BA_E    ((size_t)2 * OFF_R2)            // encoding [32,4096,64] (48 real + 16 pad)
#define BA_D1   ((size_t)2 * OFF_R1)            // dw1 out [32,4096,64]
#define BA_D2   ((size_t)2 * OFF_R3)            // upconv out [32,16384,32]

// g_wt fp32 layout
#define WT_ESW1 0
#define WT_ESB1 1728
#define WT_ESB2 1792
#define WT_ESBP 1856
#define WT_EAB1 1872
#define WT_EAB2 1936
#define WT_DB1  1968
#define WT_DB2  2032
#define WT_W3P  2064
#define WT_DB3  2928
// g_wp bf16 packed weights [t*2+c][oc][32ic] — fragment = contiguous 1KB, full lines
#define P_WP2  0
#define P_WPP  36864
#define P_WPA1 46080
#define P_WPA2 82944
#define P_WPD1 101376
#define P_WPD2 138240

__device__ __attribute__((aligned(16))) float g_ws[WS_TOTAL];
__device__ __attribute__((aligned(16))) float g_wt[3072];
__device__ __attribute__((aligned(16))) __hip_bfloat16 g_wp[156672];
__device__ int g_isbf16;

__device__ __forceinline__ float selz(bool c, float v) { return c ? v : 0.f; }
__device__ __forceinline__ float cvtbf(short s) {
    return __uint_as_float(((unsigned int)(unsigned short)s) << 16);
}
__device__ __forceinline__ short f2bf(float f) {          // RNE f32->bf16 bits
    unsigned u = __float_as_uint(f);
    u += 0x7fff + ((u >> 16) & 1);
    return (short)(u >> 16);
}
// runtime-dtype external load (adaptive — fixed-dtype builds NaN'd in rounds 1/2/7)
__device__ __forceinline__ float ldin(const void* p, size_t i, int bf) {
    return bf ? __bfloat162float(((const __hip_bfloat16*)p)[i])
              : ((const float*)p)[i];
}

// ---------------- block reductions (blockDim.x == 256) ----------------
__device__ __forceinline__ float block_sum(float v) {
    __shared__ float sb[8];
    for (int off = 32; off; off >>= 1) v += __shfl_down(v, off, 64);
    int lane = threadIdx.x & 63, wid = threadIdx.x >> 6;
    __syncthreads();
    if (lane == 0) sb[wid] = v;
    __syncthreads();
    float r = 0.f;
    for (int i = 0; i < 4; ++i) r += sb[i];
    return r;
}
__device__ __forceinline__ float block_max(float v) {
    __shared__ float sb[8];
    for (int off = 32; off; off >>= 1) v = fmaxf(v, __shfl_down(v, off, 64));
    int lane = threadIdx.x & 63, wid = threadIdx.x >> 6;
    __syncthreads();
    if (lane == 0) sb[wid] = v;
    __syncthreads();
    float r = -1e30f;
    for (int i = 0; i < 4; ++i) r = fmaxf(r, sb[i]);
    return r;
}

// ---------------- dtype probe + init ----------------
__global__ void detect_k(const void* x) {
    const __hip_bfloat16* p = (const __hip_bfloat16*)x;
    int lane = threadIdx.x & 63;
    float v = 0.f;
    for (int i = lane; i < 256; i += 64) {
        float a = fabsf(__bfloat162float(p[i]));
        if (!(a <= 2.0f)) v = 1.f;
    }
    for (int off = 32; off; off >>= 1) v += __shfl_down(v, off, 64);
    if (lane == 0) {
        g_isbf16 = (v == 0.f) ? 1 : 0;
        g_ws[OFF_REC] = 0.f;
    }
}

// ---------------- weight pack: ext dtype -> g_wt fp32 + g_wp bf16 [t*2+c][n][32] ----
__global__ void wpack_k(const void* esw1, const void* esb1, const void* esw2, const void* esb2,
                        const void* eswp, const void* esbp, const void* eaw1, const void* eab1,
                        const void* eaw2, const void* eab2, const void* dw1, const void* db1,
                        const void* dw2, const void* db2, const void* dw3, const void* db3) {
    int bf = g_isbf16;
    int gid0 = blockIdx.x * 256 + threadIdx.x, stride = gridDim.x * 256;
    for (int g = gid0; g < 512; g += stride) g_ws[OFF_HSUM + g] = 0.f;   // heat2 atomics
    for (int g = gid0; g < 1728; g += stride) g_wt[WT_ESW1 + g] = ldin(esw1, g, bf);
    for (int g = gid0; g < 64; g += stride) g_wt[WT_ESB1 + g] = ldin(esb1, g, bf);
    for (int g = gid0; g < 64; g += stride) g_wt[WT_ESB2 + g] = ldin(esb2, g, bf);
    for (int g = gid0; g < 16; g += stride) g_wt[WT_ESBP + g] = ldin(esbp, g, bf);
    for (int g = gid0; g < 64; g += stride) g_wt[WT_EAB1 + g] = ldin(eab1, g, bf);
    for (int g = gid0; g < 32; g += stride) g_wt[WT_EAB2 + g] = ldin(eab2, g, bf);
    for (int g = gid0; g < 64; g += stride) g_wt[WT_DB1 + g] = ldin(db1, g, bf);
    for (int g = gid0; g < 32; g += stride) g_wt[WT_DB2 + g] = ldin(db2, g, bf);
    for (int g = gid0; g < 3; g += stride) g_wt[WT_DB3 + g] = ldin(db3, g, bf);
    for (int g = gid0; g < 864; g += stride) {              // w3p[t][o][k]
        int t = g / 96, o = (g / 32) % 3, k = g & 31;
        g_wt[WT_W3P + g] = ldin(dw3, (size_t)(o * 32 + k) * 9 + t, bf);
    }
    // MFMA weights, fragment-contiguous layout: idx = ((t*2+c)*TOTN + n)*32 + kk,
    // src k = c*32 + kk.
    for (int g = gid0; g < 36864; g += stride) {            // wp2 (TOTN=64)
        int kk = g & 31, n = (g >> 5) & 63, tc = g >> 11;
        int t = tc >> 1, k = (tc & 1) * 32 + kk;
        g_wp[P_WP2 + g] = __float2bfloat16(ldin(esw2, (size_t)(n * 64 + k) * 9 + t, bf));
    }
    for (int g = gid0; g < 9216; g += stride) {             // wpp (TOTN=16)
        int kk = g & 31, n = (g >> 5) & 15, tc = g >> 9;
        int t = tc >> 1, k = (tc & 1) * 32 + kk;
        g_wp[P_WPP + g] = __float2bfloat16(ldin(eswp, (size_t)(n * 64 + k) * 9 + t, bf));
    }
    for (int g = gid0; g < 36864; g += stride) {            // wpa1 (TOTN=64)
        int kk = g & 31, n = (g >> 5) & 63, tc = g >> 11;
        int t = tc >> 1, k = (tc & 1) * 32 + kk;
        g_wp[P_WPA1 + g] = __float2bfloat16(ldin(eaw1, (size_t)(n * 64 + k) * 9 + t, bf));
    }
    for (int g = gid0; g < 18432; g += stride) {            // wpa2 (TOTN=32)
        int kk = g & 31, n = (g >> 5) & 31, tc = g >> 10;
        int t = tc >> 1, k = (tc & 1) * 32 + kk;
        g_wp[P_WPA2 + g] = __float2bfloat16(ldin(eaw2, (size_t)(n * 64 + k) * 9 + t, bf));
    }
    for (int g = gid0; g < 36864; g += stride) {            // wpd1 (TOTN=64, K=48 pad)
        int kk = g & 31, n = (g >> 5) & 63, tc = g >> 11;
        int t = tc >> 1, k = (tc & 1) * 32 + kk;
        float v = (k < 48) ? ldin(dw1, (size_t)(n * 48 + k) * 9 + t, bf) : 0.f;
        g_wp[P_WPD1 + g] = __float2bfloat16(v);
    }
    for (int g = gid0; g < 18432; g += stride) {            // wpd2 (TOTN=32)
        int kk = g & 31, n = (g >> 5) & 31, tc = g >> 10;
        int t = tc >> 1, k = (tc & 1) * 32 + kk;
        g_wp[P_WPD2 + g] = __float2bfloat16(ldin(dw2, (size_t)(n * 64 + k) * 9 + t, bf));
    }
}

// ---------------- conv1 both streams: stride-2 -> NHWC bf16 [64,4096,64], relu ----
__global__ void __launch_bounds__(256)
conv_s2n_k(const void* __restrict__ inA, const void* __restrict__ inB) {
    int bf = g_isbf16;
    int tile = blockIdx.x & 15;
    int b = blockIdx.x >> 4;
    const void* in = (b < 32) ? inA : inB;
    int bb = b & 31;
    int pix = tile * 256 + threadIdx.x;
    int y = pix >> 6, x = pix & 63;
    size_t inb = (size_t)bb * 3 * 16384;
    float acc[64];
    #pragma unroll
    for (int o = 0; o < 64; ++o) acc[o] = g_wt[WT_ESB1 + o];
    int iy0 = 2 * y, ix0 = 2 * x;
    bool my2 = (iy0 + 2 < 128), mx2 = (ix0 + 2 < 128);
    int iy2 = my2 ? iy0 + 2 : 127, ix2 = mx2 ? ix0 + 2 : 127;
    for (int ic = 0; ic < 3; ++ic) {
        size_t pb = inb + ic * 16384;
        float t[9];
        t[0] = ldin(in, pb + iy0 * 128 + ix0, bf);
        t[1] = ldin(in, pb + iy0 * 128 + ix0 + 1, bf);
        t[2] = selz(mx2, ldin(in, pb + iy0 * 128 + ix2, bf));
        t[3] = ldin(in, pb + (iy0 + 1) * 128 + ix0, bf);
        t[4] = ldin(in, pb + (iy0 + 1) * 128 + ix0 + 1, bf);
        t[5] = selz(mx2, ldin(in, pb + (iy0 + 1) * 128 + ix2, bf));
        t[6] = selz(my2, ldin(in, pb + iy2 * 128 + ix0, bf));
        t[7] = selz(my2, ldin(in, pb + iy2 * 128 + ix0 + 1, bf));
        t[8] = selz(my2 && mx2, ldin(in, pb + iy2 * 128 + ix2, bf));
        #pragma unroll
        for (int o = 0; o < 64; ++o) {
            const float* wr = g_wt + WT_ESW1 + (o * 3 + ic) * 9;
            float a = acc[o];
            #pragma unroll
            for (int j = 0; j < 9; ++j) a = fmaf(t[j], wr[j], a);
            acc[o] = a;
        }
    }
    __hip_bfloat16* out = (__hip_bfloat16*)g_ws + BA_XA + ((size_t)b * 4096 + pix) * 64;
    #pragma unroll
    for (int o = 0; o < 64; ++o) out[o] = __float2bfloat16(fmaxf(acc[o], 0.f));
}

// ---------------- full-channel LDS staging: TR rows x 66 px x 64 ch, swizzled ----
// 16B chunks, slot = j ^ (P & 7): px-stride 128 B — 0 conflicts for the ld_a
// access shape ONLY (j uniform per quarter-wave, P consecutive). r12 lesson.
template<int TR>
__device__ __forceinline__ void stage_tile(__hip_bfloat16* sA,
                                           const __hip_bfloat16* __restrict__ inb, int y0) {
    for (int g = threadIdx.x; g < TR * 512; g += 256) {
        int r = g >> 9;                 // 0..TR-1
        int rem = g & 511;
        int px = rem >> 3, j = rem & 7;
        int yy = y0 - 1 + r;
        int P = px + 1;
        bf8v v = (bf8v){0, 0, 0, 0, 0, 0, 0, 0};
        if (yy >= 0 && yy <= 63)
            v = *(const bf8v*)(inb + ((size_t)(yy * 64 + px) * 64 + j * 8));
        *(bf8v*)(sA + ((r * 66 + P) * 64 + ((j ^ (P & 7)) * 8))) = v;
    }
    if (threadIdx.x < TR * 16) {        // zero pads P=0 and P=65
        int g = threadIdx.x;
        int r = g >> 4, rem = g & 15, side = rem >> 3, j = rem & 7;
        int P = side ? 65 : 0;
        *(bf8v*)(sA + ((r * 66 + P) * 64 + ((j ^ (P & 7)) * 8))) = (bf8v){0, 0, 0, 0, 0, 0, 0, 0};
    }
}

// ---------------- pipelined fragment loaders (it is compile-time in unrolled loops) ---
template<int MS>
__device__ __forceinline__ void ld_a(const __hip_bfloat16* sA, int it, int rowIn,
                                     int l15, int quad, bf8v (&a)[MS]) {
    const int t = it >> 1, c = it & 1;
    const int dy = t / 3 - 1, dx = t % 3 - 1;
    const int r = rowIn + 1 + dy;
    const int j = c * 4 + quad;
    #pragma unroll
    for (int ms = 0; ms < MS; ++ms) {
        int P = ms * 16 + l15 + dx + 1;
        a[ms] = *(const bf8v*)(sA + ((r * 66 + P) * 64 + ((j ^ (P & 7)) * 8)));
    }
}
// two-row variant: loads 4-px-block fragments for rows rowbase, rowbase+1
template<int MS>
__device__ __forceinline__ void ld_a2(const __hip_bfloat16* sA, int it, int rowbase,
                                      int l15, int quad, bf8v (&a)[2][MS]) {
    const int t = it >> 1, c = it & 1;
    const int dy = t / 3 - 1, dx = t % 3 - 1;
    const int j = c * 4 + quad;
    #pragma unroll
    for (int rp = 0; rp < 2; ++rp) {
        const int r = rowbase + rp + 1 + dy;
        #pragma unroll
        for (int ms = 0; ms < MS; ++ms) {
            int P = ms * 16 + l15 + dx + 1;
            a[rp][ms] = *(const bf8v*)(sA + ((r * 66 + P) * 64 + ((j ^ (P & 7)) * 8)));
        }
    }
}
// weight fragment: it = t*2+c indexes the fragment-contiguous pack directly.
template<int TOTN, int NS>
__device__ __forceinline__ void ld_b(int it, int ocoff, int l15, int quad, int wp_off,
                                     bf8v (&bv)[NS]) {
    #pragma unroll
    for (int ns = 0; ns < NS; ++ns)
        bv[ns] = *(const bf8v*)(g_wp + wp_off +
                 ((size_t)(it * TOTN + ocoff + ns * 16 + l15) * 32 + quad * 8));
}

// ---------------- single-row MFMA body (parts pass only: NS=1, wave=row) ----------
template<int TOTN, int NS, int MS>
__device__ __forceinline__ void conv_body(const __hip_bfloat16* sA, int rowIn,
                                          int l15, int quad, int wp_off,
                                          f32x4 (&acc)[MS][NS]) {
    bf8v bq[3][NS];
    bf8v a[2][MS];
    ld_b<TOTN, NS>(0, 0, l15, quad, wp_off, bq[0]);
    ld_b<TOTN, NS>(1, 0, l15, quad, wp_off, bq[1]);
    ld_a<MS>(sA, 0, rowIn, l15, quad, a[0]);
    #pragma unroll
    for (int it = 0; it < 18; ++it) {
        if (it + 2 < 18) ld_b<TOTN, NS>(it + 2, 0, l15, quad, wp_off, bq[(it + 2) % 3]);
        if (it + 1 < 18) ld_a<MS>(sA, it + 1, rowIn, l15, quad, a[(it + 1) & 1]);
        #pragma unroll
        for (int ns = 0; ns < NS; ++ns)
            #pragma unroll
            for (int ms = 0; ms < MS; ++ms)
                acc[ms][ns] = __builtin_amdgcn_mfma_f32_16x16x32_bf16(
                    a[it & 1][ms], bq[it % 3][ns], acc[ms][ns], 0, 0, 0);
    }
}

// ---------------- 2-row x half-N MFMA body (weight-traffic-halved, r7 win) --------
template<int TOTN, int NSW, int MS>
__device__ __forceinline__ void conv_body2(const __hip_bfloat16* sA, int rowbase, int ocoff,
                                           int l15, int quad, int wp_off,
                                           f32x4 (&acc)[2][MS][NSW]) {
    bf8v bq[3][NSW];
    bf8v a[2][2][MS];
    ld_b<TOTN, NSW>(0, ocoff, l15, quad, wp_off, bq[0]);
    ld_b<TOTN, NSW>(1, ocoff, l15, quad, wp_off, bq[1]);
    ld_a2<MS>(sA, 0, rowbase, l15, quad, a[0]);
    #pragma unroll
    for (int it = 0; it < 18; ++it) {
        if (it + 2 < 18) ld_b<TOTN, NSW>(it + 2, ocoff, l15, quad, wp_off, bq[(it + 2) % 3]);
        if (it + 1 < 18) ld_a2<MS>(sA, it + 1, rowbase, l15, quad, a[(it + 1) & 1]);
        #pragma unroll
        for (int rp = 0; rp < 2; ++rp)
            #pragma unroll
            for (int ns = 0; ns < NSW; ++ns)
                #pragma unroll
                for (int ms = 0; ms < MS; ++ms)
                    acc[rp][ms][ns] = __builtin_amdgcn_mfma_f32_16x16x32_bf16(
                        a[it & 1][rp][ms], bq[it % 3][ns], acc[rp][ms][ns], 0, 0, 0);
    }
}

// ---------------- epilogue (2-row) ----------------
template<int TOTN, int NSW, int OUTF32, int RELU>
__device__ __forceinline__ void epi_2r(f32x4 (&acc)[2][4][NSW], int bO, int y0, int rowbase,
                                       int ocoff, int l15, int quad, int bias_off,
                                       size_t out_off) {
    #pragma unroll
    for (int rp = 0; rp < 2; ++rp) {
        int y = y0 + rowbase + rp;
        #pragma unroll
        for (int ns = 0; ns < NSW; ++ns) {
            float bias = g_wt[bias_off + ocoff + ns * 16 + l15];
            #pragma unroll
            for (int ms = 0; ms < 4; ++ms) {
                #pragma unroll
                for (int r = 0; r < 4; ++r) {
                    int pix = ms * 16 + quad * 4 + r;
                    float v = acc[rp][ms][ns][r] + bias;
                    if (RELU) v = fmaxf(v, 0.f);
                    size_t o = out_off + ((size_t)(bO * 4096 + y * 64 + pix)) * TOTN +
                               ocoff + ns * 16 + l15;
                    if (OUTF32) g_ws[o] = v;
                    else ((__hip_bfloat16*)g_ws)[o] = __float2bfloat16(v);
                }
            }
        }
    }
}

// ---------------- LDS-staged MFMA 3x3 conv on 64x64 NHWC (Cin=64) ----------------
// Block = 4 rows; waves = 2 row-pairs x 2 oc-halves (NSW = TOTN/32).
template<int TOTN, int NSW, int OUTF32, int RELU>
__global__ void __launch_bounds__(256) __attribute__((amdgpu_waves_per_eu(2, 3)))
conv_mfl_k(size_t in_off, int wp_off, int bias_off, size_t out_off) {
    __shared__ __hip_bfloat16 sA[6 * 66 * 64];
    int wid = threadIdx.x >> 6, lane = threadIdx.x & 63;
    int l15 = lane & 15, quad = lane >> 4;
    int b = blockIdx.x >> 4, y0 = (blockIdx.x & 15) * 4;
    int og = wid & 1, rowbase = (wid >> 1) * 2;
    int ocoff = og * NSW * 16;
    const __hip_bfloat16* inb = (const __hip_bfloat16*)g_ws + in_off + (size_t)b * 4096 * 64;
    stage_tile<6>(sA, inb, y0);
    __syncthreads();
    f32x4 acc[2][4][NSW];
    #pragma unroll
    for (int rp = 0; rp < 2; ++rp)
        #pragma unroll
        for (int ms = 0; ms < 4; ++ms)
            #pragma unroll
            for (int ns = 0; ns < NSW; ++ns) acc[rp][ms][ns] = (f32x4){0.f, 0.f, 0.f, 0.f};
    conv_body2<TOTN, NSW, 4>(sA, rowbase, ocoff, l15, quad, wp_off, acc);
    epi_2r<TOTN, NSW, OUTF32, RELU>(acc, b, y0, rowbase, ocoff, l15, quad, bias_off, out_off);
}

// ---------------- fused parts(all 64 b) + ea1(app half) from ONE X2 staging ------
// b = blockIdx&63 interleaves light/heavy blocks + pins batch b to XCD b%8.
// parts output transposed through LDS -> coalesced fp32 [b][k][4096] stores.
__global__ void __launch_bounds__(256) __attribute__((amdgpu_waves_per_eu(2, 3)))
conv_pea_k() {
    __shared__ __hip_bfloat16 sA[6 * 66 * 64];
    int wid = threadIdx.x >> 6, lane = threadIdx.x & 63;
    int l15 = lane & 15, quad = lane >> 4;
    int b = blockIdx.x & 63;
    int y0 = (int)(blockIdx.x >> 6) * 4;
    const __hip_bfloat16* inb = (const __hip_bfloat16*)g_ws + BA_X2 + (size_t)b * 4096 * 64;
    stage_tile<6>(sA, inb, y0);
    __syncthreads();
    // pass 1: parts logits (16 oc): wave = row, result kept in regs
    f32x4 accP[4][1];
    #pragma unroll
    for (int ms = 0; ms < 4; ++ms) accP[ms][0] = (f32x4){0.f, 0.f, 0.f, 0.f};
    conv_body<16, 1, 4>(sA, wid, l15, quad, P_WPP, accP);
    // pass 2: e_alpha conv1 (64 oc): wave = 2 rows x 32 oc (app half only)
    if (b >= 32) {
        int og = wid & 1, rowbase = (wid >> 1) * 2;
        int ocoff = og * 32;
        f32x4 accE[2][4][2];
        #pragma unroll
        for (int rp = 0; rp < 2; ++rp)
            #pragma unroll
            for (int ms = 0; ms < 4; ++ms)
                #pragma unroll
                for (int ns = 0; ns < 2; ++ns) accE[rp][ms][ns] = (f32x4){0.f, 0.f, 0.f, 0.f};
        conv_body2<64, 2, 4>(sA, rowbase, ocoff, l15, quad, P_WPA1, accE);
        epi_2r<64, 2, 0, 1>(accE, b - 32, y0, rowbase, ocoff, l15, quad, WT_EAB1, BA_EA1);
    }
    // transpose parts through LDS (sA no longer needed), store [b][k][4096] coalesced
    __syncthreads();
    float* tb = (float*)sA;                          // 16 k x 260-stride (16B-aligned rows)
    float biasP = g_wt[WT_ESBP + l15];
    #pragma unroll
    for (int ms = 0; ms < 4; ++ms)
        #pragma unroll
        for (int r = 0; r < 4; ++r)
            tb[l15 * 260 + wid * 64 + ms * 16 + quad * 4 + r] = accP[ms][0][r] + biasP;
    __syncthreads();
    int k = threadIdx.x >> 4, xo = (threadIdx.x & 15) * 16;
    float* dst = g_ws + OFF_PARTSF + ((size_t)(b * 16 + k)) * 4096 + y0 * 64 + xo;
    const float* src = tb + k * 260 + xo;
    #pragma unroll
    for (int i = 0; i < 16; i += 4)
        *(f32x4*)(dst + i) = *(const f32x4*)(src + i);
}

// ---------------- LDS-staged MFMA decoder conv2 + 2x nearest upsample ----------------
__global__ void __launch_bounds__(256) __attribute__((amdgpu_waves_per_eu(2, 3)))
conv_upmf2_k(size_t in_off, int wp_off, int bias_off, size_t out_off) {
    __shared__ __hip_bfloat16 sA[4 * 66 * 64];   // 33792 B -> 4 blocks/CU
    int wid = threadIdx.x >> 6, lane = threadIdx.x & 63;
    int l15 = lane & 15, quad = lane >> 4;
    int b = blockIdx.x >> 5, y0 = (blockIdx.x & 31) * 4;
    int ri0 = (y0 >> 1) - 1;
    const __hip_bfloat16* inb = (const __hip_bfloat16*)g_ws + in_off + (size_t)b * 4096 * 64;
    for (int g = threadIdx.x; g < 2048; g += 256) {
        int r = g >> 9;                 // 0..3
        int rem = g & 511;
        int px = rem >> 3, j = rem & 7;
        int yi = ri0 + r;
        int P = px + 1;
        bf8v v = (bf8v){0, 0, 0, 0, 0, 0, 0, 0};
        if (yi >= 0 && yi <= 63)
            v = *(const bf8v*)(inb + ((size_t)(yi * 64 + px) * 64 + j * 8));
        *(bf8v*)(sA + ((r * 66 + P) * 64 + ((j ^ (P & 7)) * 8))) = v;
    }
    if (threadIdx.x < 64) {             // zero pads P=0 and P=65
        int g = threadIdx.x;
        int r = g >> 4, rem = g & 15, side = rem >> 3, j = rem & 7;
        int P = side ? 65 : 0;
        *(bf8v*)(sA + ((r * 66 + P) * 64 + ((j ^ (P & 7)) * 8))) = (bf8v){0, 0, 0, 0, 0, 0, 0, 0};
    }
    __syncthreads();
    int og = wid & 1, rowbase = (wid >> 1) * 2;
    f32x4 acc[2][8];
    #pragma unroll
    for (int rp = 0; rp < 2; ++rp)
        #pragma unroll
        for (int ms = 0; ms < 8; ++ms) acc[rp][ms] = (f32x4){0.f, 0.f, 0.f, 0.f};
    bf8v bq[3][1];
    ld_b<32, 1>(0, og * 16, l15, quad, wp_off, bq[0]);
    ld_b<32, 1>(1, og * 16, l15, quad, wp_off, bq[1]);
    #pragma unroll
    for (int it = 0; it < 18; ++it) {
        if (it + 2 < 18) ld_b<32, 1>(it + 2, og * 16, l15, quad, wp_off, bq[(it + 2) % 3]);
        const int t = it >> 1, c = it & 1;
        const int dy = t / 3 - 1, dx = t % 3 - 1;
        #pragma unroll
        for (int rp = 0; rp < 2; ++rp) {
            int yy = y0 + rowbase + rp + dy;
            if (yy >= 0 && yy <= 127) {       // wave-uniform per rp
                int r = (yy >> 1) - ri0;      // 0..3
                int j = c * 4 + quad;
                bf8v a[8];
                #pragma unroll
                for (int ms = 0; ms < 8; ++ms) {
                    int xx = ms * 16 + l15 + dx;
                    int P = (xx < 0) ? 0 : ((xx > 127) ? 65 : ((xx >> 1) + 1));
                    a[ms] = *(const bf8v*)(sA + ((r * 66 + P) * 64 + ((j ^ (P & 7)) * 8)));
                }
                #pragma unroll
                for (int ms = 0; ms < 8; ++ms)
                    acc[rp][ms] = __builtin_amdgcn_mfma_f32_16x16x32_bf16(a[ms], bq[it % 3][0], acc[rp][ms], 0, 0, 0);
            }
        }
    }
    float bias = g_wt[bias_off + og * 16 + l15];
    #pragma unroll
    for (int rp = 0; rp < 2; ++rp) {
        int y = y0 + rowbase + rp;
        #pragma unroll
        for (int ms = 0; ms < 8; ++ms) {
            #pragma unroll
            for (int r = 0; r < 4; ++r) {
                int pix = ms * 16 + quad * 4 + r;
                float v = fmaxf(acc[rp][ms][r] + bias, 0.f);
                size_t o = out_off + ((size_t)(b * 16384 + y * 128 + pix)) * 32 + og * 16 + l15;
                ((__hip_bfloat16*)g_ws)[o] = __float2bfloat16(v);
            }
        }
    }
}

// ---------------- fused softmax+moments: parts logits fp32 [b][k][4096] ----------------
__global__ void sm_mom3_k() {
    int bk = blockIdx.x;
    int b = bk >> 4;
    int app = (b >= 32);
    const float* P = g_ws + OFF_PARTSF + (size_t)bk * 4096;
    float r[16];
    #pragma unroll
    for (int j = 0; j < 16; ++j) r[j] = P[threadIdx.x + j * 256];
    float m = r[0];
    #pragma unroll
    for (int j = 1; j < 16; ++j) m = fmaxf(m, r[j]);
    m = block_max(m);
    float s = 0.f;
    #pragma unroll
    for (int j = 0; j < 16; ++j) { r[j] = __expf(r[j] - m); s += r[j]; }
    s = block_sum(s);
    float inv = 1.0f / s;
    float sy = 0, sx = 0, syy = 0, sxy = 0, sxx = 0;
    #pragma unroll
    for (int j = 0; j < 16; ++j) {
        float pv = r[j] * inv;
        int i = threadIdx.x + j * 256;
        if (app) g_ws[OFF_PROBS + (size_t)(bk - 512) * 4096 + i] = pv;
        float gy = -1.0f + (i >> 6) * (2.0f / 63.0f);
        float gx = -1.0f + (i & 63) * (2.0f / 63.0f);
        sy += pv * gy; sx += pv * gx;
        syy += pv * gy * gy; sxy += pv * gy * gx; sxx += pv * gx * gx;
    }
    sy = block_sum(sy); sx = block_sum(sx);
    syy = block_sum(syy); sxy = block_sum(sxy); sxx = block_sum(sxx);
    if (threadIdx.x == 0) {
        float c00 = syy - sy * sy, c01 = sxy - sy * sx, c11 = sxx - sx * sx;
        float a = sqrtf(fmaxf(c00 + EPS, 1e-12f));
        float bb = c01 / (a + EPS);
        float cc = sqrtf(fmaxf(c11 - bb * bb, 0.f) + EPS);
        float det = a * cc;
        float sc = SCAL / (det + EPS);
        int idx = app ? (bk - 512) : bk;
        int mu_off = app ? OFF_MUA : OFF_MU;
        int linv_off = app ? OFF_LINVA : OFF_LINV;
        g_ws[mu_off + idx * 2 + 0] = sy;
        g_ws[mu_off + idx * 2 + 1] = sx;
        g_ws[linv_off + idx * 4 + 0] = cc * sc;
        g_ws[linv_off + idx * 4 + 1] = 0.f;
        g_ws[linv_off + idx * 4 + 2] = -bb * sc;
        g_ws[linv_off + idx * 4 + 3] = a * sc;
    }
}

// ---------------- alpha[b,k,f] = sum_hw probs[b,k,hw] * fxs[b,hw,f] (both fp32) ----------------
__global__ void alpha2_k() {
    int b = blockIdx.x & 31, k = blockIdx.x >> 5;
    int bk = b * 16 + k;
    __shared__ float pl[4096];
    const float* pr = g_ws + OFF_PROBS + (size_t)bk * 4096;
    for (int i = threadIdx.x; i < 4096; i += 256) pl[i] = pr[i];
    __syncthreads();
    float acc[32];
    #pragma unroll
    for (int f = 0; f < 32; ++f) acc[f] = 0.f;
    for (int i = threadIdx.x; i < 4096; i += 256) {
        float pv = pl[i];
        const float* fp = g_ws + OFF_FXS + (size_t)(b * 4096 + i) * 32;
        #pragma unroll
        for (int f = 0; f < 32; ++f) acc[f] = fmaf(pv, fp[f], acc[f]);
    }
    __shared__ float sw[4][32];
    int lane = threadIdx.x & 63, wid = threadIdx.x >> 6;
    #pragma unroll
    for (int f = 0; f < 32; ++f)
        for (int off = 32; off; off >>= 1) acc[f] += __shfl_down(acc[f], off, 64);
    if (lane == 0) {
        #pragma unroll
        for (int f = 0; f < 32; ++f) sw[wid][f] = acc[f];
    }
    __syncthreads();
    if (threadIdx.x < 32)
        g_ws[OFF_ALPHA + bk * 32 + threadIdx.x] =
            sw[0][threadIdx.x] + sw[1][threadIdx.x] + sw[2][threadIdx.x] + sw[3][threadIdx.x];
}

// ---------------- heat -> E NHWC bf16 ch[0..16) vector writes, + hsum atomics ----------------
__global__ void heat2_k() {
    int tile = blockIdx.x & 15, b = blockIdx.x >> 4;
    __shared__ float hs[16];
    if (threadIdx.x < 16) hs[threadIdx.x] = 0.f;
    __syncthreads();
    int pix = tile * 256 + threadIdx.x;
    float gy = -1.0f + (pix >> 6) * (2.0f / 63.0f);
    float gx = -1.0f + (pix & 63) * (2.0f / 63.0f);
    bf8v e0, e1;
    float hv[16];
    #pragma unroll
    for (int k = 0; k < 16; ++k) {
        int bk = b * 16 + k;
        float m0 = g_ws[OFF_MU + bk * 2], m1 = g_ws[OFF_MU + bk * 2 + 1];
        float L00 = g_ws[OFF_LINV + bk * 4 + 0], L10 = g_ws[OFF_LINV + bk * 4 + 2],
              L11 = g_ws[OFF_LINV + bk * 4 + 3];
        float d0 = gy - m0, d1 = gx - m1;
        float p0 = d0 * L00 + d1 * L10;
        float p1 = d1 * L11;
        float h = 1.0f / (1.0f + p0 * p0 + p1 * p1);
        hv[k] = h;
        short sbits = f2bf(h);
        if (k < 8) e0[k] = sbits; else e1[k - 8] = sbits;
    }
    __hip_bfloat16* E = (__hip_bfloat16*)g_ws + BA_E + (size_t)(b * 4096 + pix) * 64;
    *(bf8v*)E = e0;
    *(bf8v*)(E + 8) = e1;
    #pragma unroll
    for (int k = 0; k < 16; ++k) {
        float v = hv[k];
        for (int off = 32; off; off >>= 1) v += __shfl_down(v, off, 64);
        if ((threadIdx.x & 63) == 0) atomicAdd(&hs[k], v);
    }
    __syncthreads();
    if (threadIdx.x < 16)
        atomicAdd(&g_ws[OFF_HSUM + b * 16 + threadIdx.x], hs[threadIdx.x]);
}

// ---------------- fmap -> E ch[16..48), zero ch[48..64) ----------------
__global__ void fmap2_k() {
    int tile = blockIdx.x & 15, b = blockIdx.x >> 4;
    __shared__ float coef[16][32];
    for (int i = threadIdx.x; i < 512; i += 256) {
        int k = i >> 5, f = i & 31;
        coef[k][f] = g_ws[OFF_ALPHA + (b * 16 + k) * 32 + f] /
                     (g_ws[OFF_HSUM + b * 16 + k] + EPS);
    }
    __syncthreads();
    int pix = tile * 256 + threadIdx.x;
    __hip_bfloat16* E = (__hip_bfloat16*)g_ws + BA_E + (size_t)(b * 4096 + pix) * 64;
    float h[16];
    #pragma unroll
    for (int k = 0; k < 16; ++k) h[k] = __bfloat162float(E[k]);
    #pragma unroll
    for (int f = 0; f < 32; ++f) {
        float a = 0.f;
        #pragma unroll
        for (int k = 0; k < 16; ++k) a = fmaf(h[k], coef[k][f], a);
        E[16 + f] = __float2bfloat16(a);
    }
    #pragma unroll
    for (int z = 48; z < 64; ++z) E[z] = __float2bfloat16(0.f);
}

// ---------------- final conv(32->3) + sigmoid -> out, fused rec-loss ----------------
// r13: tap double-buffer + two independent pixel chains (allocator cannot merge).
__device__ __forceinline__ void ld_tap9(const short* __restrict__ D2, int y, int x, int t,
                                        bf8v (&dst)[4]) {
    int dy = t / 3 - 1, dx = t % 3 - 1;
    int yy = y + dy, xx = x + dx;
    bool ok = ((unsigned)yy < 128u) && ((unsigned)xx < 128u);
    const short* sp = D2 + (size_t)((ok ? yy : y) * 128 + (ok ? xx : x)) * 32;
    const bf8v zv = (bf8v){0, 0, 0, 0, 0, 0, 0, 0};
    #pragma unroll
    for (int c = 0; c < 4; ++c) {
        bf8v tmp = *(const bf8v*)(sp + c * 8);
        dst[c] = ok ? tmp : zv;
    }
}
__device__ __forceinline__ void fma_tap(const bf8v (&v)[4], int t, float (&acc)[3]) {
    #pragma unroll
    for (int c = 0; c < 4; ++c)
        #pragma unroll
        for (int j = 0; j < 8; ++j) {
            float av = cvtbf(v[c][j]);
            int kk = c * 8 + j;
            acc[0] = fmaf(av, g_wt[WT_W3P + (t * 3 + 0) * 32 + kk], acc[0]);
            acc[1] = fmaf(av, g_wt[WT_W3P + (t * 3 + 1) * 32 + kk], acc[1]);
            acc[2] = fmaf(av, g_wt[WT_W3P + (t * 3 + 2) * 32 + kk], acc[2]);
        }
}
__global__ void __launch_bounds__(256)
conv_sign_k(const void* __restrict__ ximg, void* __restrict__ outp) {
    int bf = g_isbf16;
    int tile = blockIdx.x & 31, b = blockIdx.x >> 5;
    int pix0 = tile * 512 + threadIdx.x;
    int pix1 = pix0 + 256;
    int y0p = pix0 >> 7, x0p = pix0 & 127;
    int y1p = pix1 >> 7, x1p = pix1 & 127;
    const short* D2 = (const short*)((const __hip_bfloat16*)g_ws + BA_D2 + (size_t)b * 16384 * 32);
    float acc0[3], acc1[3];
    #pragma unroll
    for (int o = 0; o < 3; ++o) { acc0[o] = g_wt[WT_DB3 + o]; acc1[o] = acc0[o]; }
    bf8v vA0[4], vB0[4], vA1[4], vB1[4];
    ld_tap9(D2, y0p, x0p, 0, vA0);
    ld_tap9(D2, y1p, x1p, 0, vA1);
    #pragma unroll 1
    for (int tt = 0; tt < 4; ++tt) {          // taps 2tt, 2tt+1; preload 2tt+2
        int t0 = 2 * tt, t1 = 2 * tt + 1;
        ld_tap9(D2, y0p, x0p, t1, vB0);
        ld_tap9(D2, y1p, x1p, t1, vB1);
        fma_tap(vA0, t0, acc0);
        fma_tap(vA1, t0, acc1);
        ld_tap9(D2, y0p, x0p, t1 + 1, vA0);   // t1+1 <= 8, always valid tap
        ld_tap9(D2, y1p, x1p, t1 + 1, vA1);
        fma_tap(vB0, t1, acc0);
        fma_tap(vB1, t1, acc1);
    }
    fma_tap(vA0, 8, acc0);
    fma_tap(vA1, 8, acc1);
    float es = 0.f;
    #pragma unroll
    for (int o = 0; o < 3; ++o) {
        float v = 1.0f / (1.0f + __expf(-acc0[o]));
        size_t oidx = ((size_t)b * 3 + o) * 16384 + pix0;
        if (bf) ((__hip_bfloat16*)outp)[oidx] = __float2bfloat16(v);
        else    ((float*)outp)[oidx] = v;
        float e = ldin(ximg, oidx, bf) - v;
        es += e * e;
        float v1 = 1.0f / (1.0f + __expf(-acc1[o]));
        size_t oidx1 = ((size_t)b * 3 + o) * 16384 + pix1;
        if (bf) ((__hip_bfloat16*)outp)[oidx1] = __float2bfloat16(v1);
        else    ((float*)outp)[oidx1] = v1;
        float e1 = ldin(ximg, oidx1, bf) - v1;
        es += e1 * e1;
    }
    float s = block_sum(es);
    if (threadIdx.x == 0) atomicAdd(&g_ws[OFF_REC], s);
}

// ---------------- scalar loss ----------------
__global__ void loss_k(const void* __restrict__ coord,
                       const void* __restrict__ vec,
                       void* __restrict__ outp) {
    int bf = g_isbf16;
    const float* mu = g_ws + OFF_MU;
    const float* linv = g_ws + OFF_LINV;
    const float* mu_a = g_ws + OFF_MUA;
    const float* linv_a = g_ws + OFF_LINVA;
    float s1 = 0, s2 = 0, s3 = 0;
    for (int i = threadIdx.x; i < 1024; i += 256) {
        float d = mu[i] - mu_a[i];
        s1 += d * d;
        float t = ldin(coord, i, bf) + ldin(vec, i, bf);
        float d3 = mu_a[i] - t;
        s3 += d3 * d3;
    }
    for (int i = threadIdx.x; i < 2048; i += 256) {
        float d = linv[i] - linv_a[i];
        s2 += d * d;
    }
    s1 = block_sum(s1);
    s2 = block_sum(s2);
    s3 = block_sum(s3);
    if (threadIdx.x == 0) {
        float loss = g_ws[OFF_REC] / 1572864.0f + s1 / 1024.0f + 0.01f * (s2 / 2048.0f)
                   + s3 / 1024.0f;
        if (bf) ((__hip_bfloat16*)outp)[1572864] = __float2bfloat16(loss);
        else    ((float*)outp)[1572864] = loss;
    }
}

extern "C" void kernel_launch(void* const* d_in, const int* in_sizes, int n_in,
                              void* d_out, int out_size, void* d_ws, size_t ws_size,
                              hipStream_t stream) {
    const void* x     = d_in[0];
    const void* x_st  = d_in[1];
    const void* x_at  = d_in[2];
    const void* coord = d_in[3];
    const void* vec   = d_in[4];

    dim3 blk(256);

    detect_k<<<1, 64, 0, stream>>>(x);
    wpack_k<<<64, blk, 0, stream>>>(
        d_in[5],  d_in[6],  d_in[7],  d_in[8],
        d_in[9],  d_in[10], d_in[11], d_in[12],
        d_in[13], d_in[14], d_in[15], d_in[16],
        d_in[17], d_in[18], d_in[19], d_in[20]);

    // ---- encoder (B=64 batched, NHWC bf16): conv1 (merged 64-oc) -> XA; conv2 -> X2 ----
    conv_s2n_k<<<64 * 16, blk, 0, stream>>>(x_at, x_st);
    conv_mfl_k<64, 2, 0, 1><<<1024, blk, 0, stream>>>(BA_XA, P_WP2, WT_ESB2, BA_X2);

    // ---- fused: parts logits (all b, k-major via LDS transpose) + ea1 (app half) ----
    conv_pea_k<<<1024, blk, 0, stream>>>();
    sm_mom3_k<<<1024, blk, 0, stream>>>();

    // ---- e_alpha conv2 -> FXS fp32; alpha (XCD-swizzled) ----
    conv_mfl_k<32, 1, 1, 0><<<512, blk, 0, stream>>>(BA_EA1, P_WPA2, WT_EAB2, (size_t)OFF_FXS);
    alpha2_k<<<512, blk, 0, stream>>>();

    // ---- encoding E (NHWC bf16, 48+16pad): heat (vectorized) + fmap ----
    heat2_k<<<512, blk, 0, stream>>>();
    fmap2_k<<<512, blk, 0, stream>>>();

    // ---- decoder: dw1(MFMA+LDS) -> D1; upconv(MFMA+LDS) -> D2; sig conv -> out ----
    conv_mfl_k<64, 2, 0, 1><<<512, blk, 0, stream>>>(BA_E, P_WPD1, WT_DB1, BA_D1);
    conv_upmf2_k<<<1024, blk, 0, stream>>>(BA_D1, P_WPD2, WT_DB2, BA_D2);
    conv_sign_k<<<32 * 32, blk, 0, stream>>>(x, d_out);

    // ---- loss ----
    loss_k<<<1, blk, 0, stream>>>(coord, vec, d_out);
}